// Round 6
// baseline (46.764 us; speedup 1.0000x reference)
//
#include <hip/hip_runtime.h>
#include <hip/hip_bf16.h>
#include <math.h>

// MultiVariateAttention: out[b,u] = exp(mvn_logpdf(x[b]; mu[u], diag(s[u])))
// B = U = 4096, D = 16, fp32 in/out.
//
// R6 = DECOMPOSITION EXPERIMENT: exact R3 kernel (best measured, 28.6us),
// with the main kernel launched TWICE (idempotent rewrite of the same
// values -> correctness and determinism unchanged).
//   dur_R6 = pre + 2*main + overhead;  dur_R3 = pre + main + overhead
//   => main = dur_R6 - dur_R3. Resolves whether ~30us is main-kernel time
//   (store path) or precompute/launch/replay overhead.

#define TPB 256
#define DD 16
#define UPT 2      // u's per thread: params = 66 VGPR, float2 stores
#define BPB 32     // b rows per block -> grid 1024 = 4 blocks/CU

static constexpr float L2E   = 1.4426950408889634f;   // log2(e)
static constexpr float HL2PI = 0.91893853320467274f;  // 0.5*ln(2*pi)

// P layout: [2*D+1][U]. rows 0..15 = A1[d], 16..31 = A2[d], 32 = bias.
__global__ __launch_bounds__(TPB) void mva_precompute(
    const float* __restrict__ units, const float* __restrict__ attn,
    float* __restrict__ P, int U)
{
    int g = blockIdx.x * TPB + threadIdx.x;
    int u = g >> 4, d = g & 15;
    float s  = fmaxf(attn[(size_t)u * DD * DD + d * (DD + 1)], 1e-6f);
    float w  = 1.f / (s * s);
    float mu = units[g];
    P[(size_t)d * U + u]        = L2E * mu * w;
    P[(size_t)(DD + d) * U + u] = -0.5f * L2E * w;
    float bn = -0.5f * mu * mu * w - logf(s);
    bn += __shfl_xor(bn, 1, 16);
    bn += __shfl_xor(bn, 2, 16);
    bn += __shfl_xor(bn, 4, 16);
    bn += __shfl_xor(bn, 8, 16);
    if (d == 0) P[(size_t)(2 * DD) * U + u] = L2E * (bn - DD * HL2PI);
}

template <bool USE_WS>
__global__ __launch_bounds__(TPB, 4) void mva_main(
    const float* __restrict__ x,      // [B,1,D]
    const float* __restrict__ P,      // [33][U] when USE_WS
    const float* __restrict__ units,  // raw params when !USE_WS
    const float* __restrict__ attn,
    float* __restrict__ out, int U)
{
    const int u0 = blockIdx.y * (TPB * UPT) + threadIdx.x * UPT;
    const int b0 = blockIdx.x * BPB;

    __shared__ float xs[BPB][DD];
    for (int idx = threadIdx.x; idx < BPB * DD; idx += TPB) {
        xs[idx >> 4][idx & 15] = x[(size_t)b0 * DD + idx];
    }

    float a1[UPT][DD], a2[UPT][DD], bias[UPT];
    if (USE_WS) {
#pragma unroll
        for (int d = 0; d < DD; ++d) {
            float2 v = *reinterpret_cast<const float2*>(P + (size_t)d * U + u0);
            a1[0][d] = v.x; a1[1][d] = v.y;
            float2 w = *reinterpret_cast<const float2*>(P + (size_t)(DD + d) * U + u0);
            a2[0][d] = w.x; a2[1][d] = w.y;
        }
        float2 bv = *reinterpret_cast<const float2*>(P + (size_t)(2 * DD) * U + u0);
        bias[0] = bv.x; bias[1] = bv.y;
    } else {
#pragma unroll
        for (int i = 0; i < UPT; ++i) {
            int u = u0 + i;
            float bn = 0.f;
#pragma unroll
            for (int d = 0; d < DD; ++d) {
                float s  = fmaxf(attn[(size_t)u * DD * DD + d * (DD + 1)], 1e-6f);
                float w  = 1.f / (s * s);
                float mu = units[u * DD + d];
                a1[i][d] = L2E * mu * w;
                a2[i][d] = -0.5f * L2E * w;
                bn += -0.5f * mu * mu * w - logf(s);
            }
            bias[i] = L2E * (bn - DD * HL2PI);
        }
    }
    __syncthreads();

#pragma unroll 2
    for (int b = 0; b < BPB; ++b) {
        float acc[UPT];
#pragma unroll
        for (int i = 0; i < UPT; ++i) acc[i] = bias[i];
#pragma unroll
        for (int j = 0; j < 4; ++j) {
            float4 xv = *reinterpret_cast<const float4*>(&xs[b][4 * j]);
#pragma unroll
            for (int k = 0; k < 4; ++k) {
                float xd = (&xv.x)[k];
                int d = 4 * j + k;
#pragma unroll
                for (int i = 0; i < UPT; ++i) {
                    float t = fmaf(xd, a2[i][d], a1[i][d]);
                    acc[i]  = fmaf(xd, t, acc[i]);
                }
            }
        }
        float2 o;
        o.x = __builtin_amdgcn_exp2f(acc[0]);
        o.y = __builtin_amdgcn_exp2f(acc[1]);
        *reinterpret_cast<float2*>(out + (size_t)(b0 + b) * U + u0) = o;
    }
}

extern "C" void kernel_launch(void* const* d_in, const int* in_sizes, int n_in,
                              void* d_out, int out_size, void* d_ws, size_t ws_size,
                              hipStream_t stream) {
    const float* x     = (const float*)d_in[0];  // [B,1,D]
    const float* units = (const float*)d_in[1];  // [U,D]
    const float* attn  = (const float*)d_in[2];  // [U,D,D]
    float* out = (float*)d_out;

    const int B = in_sizes[0] / DD;  // 4096
    const int U = in_sizes[1] / DD;  // 4096

    dim3 grid(B / BPB, U / (TPB * UPT));  // (128, 8) = 1024 blocks
    size_t pbytes = (size_t)(2 * DD + 1) * U * sizeof(float);

    if (ws_size >= pbytes) {
        float* P = (float*)d_ws;
        mva_precompute<<<(U * DD) / TPB, TPB, 0, stream>>>(units, attn, P, U);
        // Launched twice on purpose: second pass rewrites identical values.
        // dur_R6 - dur_R3 isolates the main kernel's true duration.
        mva_main<true><<<grid, TPB, 0, stream>>>(x, P, units, attn, out, U);
        mva_main<true><<<grid, TPB, 0, stream>>>(x, P, units, attn, out, U);
    } else {
        mva_main<false><<<grid, TPB, 0, stream>>>(x, nullptr, units, attn, out, U);
        mva_main<false><<<grid, TPB, 0, stream>>>(x, nullptr, units, attn, out, U);
    }
}

// Round 7
// 29.750 us; speedup vs baseline: 1.5719x; 1.5719x over previous
//
#include <hip/hip_runtime.h>
#include <hip/hip_bf16.h>
#include <math.h>

// MultiVariateAttention: out[b,u] = exp(mvn_logpdf(x[b]; mu[u], diag(s[u])))
// B = U = 4096, D = 16, fp32 in/out.
//
// R6 decomposition: main ~= 18.2us (vs ~11us store floor), pre+gap ~= 10.4us.
// R7 levers:
//  pre-v2: coalesced attn panel load through LDS (was: 1 line per 4B) and
//          coalesced P writes via transpose tile (was: 64 lines/wave-store).
//  main-v2: UPT=4 + float4 stores -> 1KB per wave store instruction, 4KB
//          contiguous per block b-row (was 512B granules, 16KB stride);
//          4 independent acc chains = full FMA ILP. No launch_bounds min
//          (R5 lesson: forcing 6 waves/SIMD at ~100 live VGPRs spills).

#define TPB 256
#define DD 16
#define UPT 4      // u's per thread: params = 132 VGPR, float4 stores
#define BPB 32     // b rows per block -> grid (128,4) = 512 blocks

static constexpr float L2E   = 1.4426950408889634f;   // log2(e)
static constexpr float HL2PI = 0.91893853320467274f;  // 0.5*ln(2*pi)

// P layout: [2*D+1][U]. rows 0..15 = A1[d], 16..31 = A2[d], 32 = bias.
// One block per 16 u. attn panel (16KB) staged via coalesced float4 loads.
__global__ __launch_bounds__(TPB) void mva_precompute(
    const float* __restrict__ units, const float* __restrict__ attn,
    float* __restrict__ P, int U)
{
    const int tid   = threadIdx.x;
    const int u_blk = blockIdx.x * (TPB / DD);   // 16 u per block

    // Coalesced stage of attn[u_blk..u_blk+15][*][*]: 4096 floats.
    __shared__ float ap[DD * DD * (TPB / DD)];
    const float* base = attn + (size_t)u_blk * DD * DD;
#pragma unroll
    for (int r = 0; r < 4; ++r) {
        *reinterpret_cast<float4*>(&ap[(r * TPB + tid) * 4]) =
            *reinterpret_cast<const float4*>(base + (size_t)(r * TPB + tid) * 4);
    }
    __syncthreads();

    const int ul = tid >> 4, d = tid & 15;
    float s  = fmaxf(ap[ul * DD * DD + d * (DD + 1)], 1e-6f);
    float w  = 1.f / (s * s);
    float mu = units[u_blk * DD + tid];  // == units[(u_blk+ul)*DD + d], coalesced
    float bn = -0.5f * mu * mu * w - logf(s);
    bn += __shfl_xor(bn, 1, 16);
    bn += __shfl_xor(bn, 2, 16);
    bn += __shfl_xor(bn, 4, 16);
    bn += __shfl_xor(bn, 8, 16);

    __shared__ float tile[2 * DD + 1][TPB / DD];
    tile[d][ul]      = L2E * mu * w;
    tile[DD + d][ul] = -0.5f * L2E * w;
    if (d == 0) tile[2 * DD][ul] = L2E * (bn - DD * HL2PI);
    __syncthreads();

    // P writes: 4 full 64B lines per wave store round.
    for (int i = tid; i < (2 * DD + 1) * (TPB / DD); i += TPB) {
        P[(size_t)(i >> 4) * U + u_blk + (i & 15)] = tile[i >> 4][i & 15];
    }
}

template <bool USE_WS>
__global__ __launch_bounds__(TPB) void mva_main(
    const float* __restrict__ x,      // [B,1,D]
    const float* __restrict__ P,      // [33][U] when USE_WS
    const float* __restrict__ units,  // raw params when !USE_WS
    const float* __restrict__ attn,
    float* __restrict__ out, int U)
{
    const int u0 = blockIdx.y * (TPB * UPT) + threadIdx.x * UPT;
    const int b0 = blockIdx.x * BPB;

    __shared__ float xs[BPB][DD];
    for (int idx = threadIdx.x; idx < BPB * DD; idx += TPB) {
        xs[idx >> 4][idx & 15] = x[(size_t)b0 * DD + idx];
    }

    float a1[UPT][DD], a2[UPT][DD], bias[UPT];
    if (USE_WS) {
#pragma unroll
        for (int d = 0; d < DD; ++d) {
            float4 v = *reinterpret_cast<const float4*>(P + (size_t)d * U + u0);
            a1[0][d] = v.x; a1[1][d] = v.y; a1[2][d] = v.z; a1[3][d] = v.w;
            float4 w = *reinterpret_cast<const float4*>(P + (size_t)(DD + d) * U + u0);
            a2[0][d] = w.x; a2[1][d] = w.y; a2[2][d] = w.z; a2[3][d] = w.w;
        }
        float4 bv = *reinterpret_cast<const float4*>(P + (size_t)(2 * DD) * U + u0);
        bias[0] = bv.x; bias[1] = bv.y; bias[2] = bv.z; bias[3] = bv.w;
    } else {
#pragma unroll
        for (int i = 0; i < UPT; ++i) {
            int u = u0 + i;
            float bn = 0.f;
#pragma unroll
            for (int d = 0; d < DD; ++d) {
                float s  = fmaxf(attn[(size_t)u * DD * DD + d * (DD + 1)], 1e-6f);
                float w  = 1.f / (s * s);
                float mu = units[u * DD + d];
                a1[i][d] = L2E * mu * w;
                a2[i][d] = -0.5f * L2E * w;
                bn += -0.5f * mu * mu * w - logf(s);
            }
            bias[i] = L2E * (bn - DD * HL2PI);
        }
    }
    __syncthreads();

#pragma unroll 2
    for (int b = 0; b < BPB; ++b) {
        float acc[UPT];
#pragma unroll
        for (int i = 0; i < UPT; ++i) acc[i] = bias[i];
#pragma unroll
        for (int j = 0; j < 4; ++j) {
            // Wave-uniform LDS address -> broadcast, conflict-free.
            float4 xv = *reinterpret_cast<const float4*>(&xs[b][4 * j]);
#pragma unroll
            for (int k = 0; k < 4; ++k) {
                float xd = (&xv.x)[k];
                int d = 4 * j + k;
#pragma unroll
                for (int i = 0; i < UPT; ++i) {
                    float t = fmaf(xd, a2[i][d], a1[i][d]);
                    acc[i]  = fmaf(xd, t, acc[i]);
                }
            }
        }
        float4 o;
        o.x = __builtin_amdgcn_exp2f(acc[0]);
        o.y = __builtin_amdgcn_exp2f(acc[1]);
        o.z = __builtin_amdgcn_exp2f(acc[2]);
        o.w = __builtin_amdgcn_exp2f(acc[3]);
        *reinterpret_cast<float4*>(out + (size_t)(b0 + b) * U + u0) = o;
    }
}

extern "C" void kernel_launch(void* const* d_in, const int* in_sizes, int n_in,
                              void* d_out, int out_size, void* d_ws, size_t ws_size,
                              hipStream_t stream) {
    const float* x     = (const float*)d_in[0];  // [B,1,D]
    const float* units = (const float*)d_in[1];  // [U,D]
    const float* attn  = (const float*)d_in[2];  // [U,D,D]
    float* out = (float*)d_out;

    const int B = in_sizes[0] / DD;  // 4096
    const int U = in_sizes[1] / DD;  // 4096

    dim3 grid(B / BPB, U / (TPB * UPT));  // (128, 4) = 512 blocks
    size_t pbytes = (size_t)(2 * DD + 1) * U * sizeof(float);

    if (ws_size >= pbytes) {
        float* P = (float*)d_ws;
        mva_precompute<<<U / (TPB / DD), TPB, 0, stream>>>(units, attn, P, U);
        mva_main<true><<<grid, TPB, 0, stream>>>(x, P, units, attn, out, U);
    } else {
        mva_main<false><<<grid, TPB, 0, stream>>>(x, nullptr, units, attn, out, U);
    }
}